// Round 8
// baseline (2490.194 us; speedup 1.0000x reference)
//
#include <hip/hip_runtime.h>
#include <math.h>

static constexpr int NB = 8, NT = 10, E = 32;
static constexpr int H1 = 30, W1 = 30, F1 = 256, G1 = 1024;
static constexpr int H2 = 28, W2 = 28, F2 = 128, G2 = 512;

typedef _Float16 half8 __attribute__((ext_vector_type(8)));
typedef float f32x4 __attribute__((ext_vector_type(4)));

__device__ __forceinline__ float sigf(float v){ return 1.0f/(1.0f + __expf(-v)); }

// ================= layer-1 MFMA body (one step, t>=1) =================
// 480 blocks = 8b * 15 row-pairs * 4 ch-quarters; 256 thr (4 waves)
__device__ __forceinline__
void l1_body(char* smem, int bid, int tid,
             const float* __restrict__ x, const _Float16* __restrict__ Wh1t,
             const float* __restrict__ Wx1, const float* __restrict__ b1,
             const _Float16* __restrict__ h_prev, _Float16* __restrict__ h_out,
             float* __restrict__ c_st, int t)
{
    _Float16* Alds = (_Float16*)smem;     // 4*32*128 fp16 = 32 KB

    const int nq  = bid & 3;
    const int tmp = bid >> 2;
    const int rp  = tmp % 15;
    const int b   = tmp / 15;
    const int y0  = rp*2;

    const int w    = tid >> 6;
    const int lane = tid & 63;
    const int l15  = lane & 15;
    const int l16  = lane >> 4;
    const int c    = nq*64 + w*16 + l15;          // output channel 0..255

    f32x4 acc[4][4];
    #pragma unroll
    for (int mt=0; mt<4; ++mt)
        #pragma unroll
        for (int q=0; q<4; ++q) acc[mt][q] = (f32x4){0.f,0.f,0.f,0.f};

    int goff[4];
    #pragma unroll
    for (int q=0; q<4; ++q) goff[q] = ((q*256 + nq*64 + w*16 + l15)<<8) + (l16<<3);

    for (int cih=0; cih<2; ++cih){
        __syncthreads();
        #pragma unroll
        for (int it=0; it<8; ++it){
            int e = tid + (it<<8);
            int ci8 = e & 15, xx = (e>>4)&31, r = e>>9;
            int gy = y0 - 1 + r, gx = xx - 1;
            uint4 v = {0u,0u,0u,0u};
            if (gy >= 0 && gy < 30 && gx >= 0 && gx < 30)
                v = *(const uint4*)(const void*)(h_prev + ((((b*30+gy)*30+gx))<<8) + (cih<<7) + (ci8<<3));
            *(uint4*)(void*)((char*)Alds + ((((((r<<5)+xx))<<8) + (ci8<<4)) ^ ((xx&7)<<4))) = v;
        }
        __syncthreads();

        const _Float16* Bc = Wh1t + (cih<<7);
        auto gloadq = [&](half8 (&dst)[4], int nsl){
            const _Float16* src = Bc + (((size_t)(nsl>>2))<<18) + ((nsl&3)<<5);
            #pragma unroll
            for (int q=0; q<4; ++q)
                dst[q] = *(const half8*)(const void*)(src + goff[q]);
        };

        half8 bA[4], bB[4];
        gloadq(bA, 0);
        gloadq(bB, 1);
        int sl = 0;
        for (int tap=0; tap<9; ++tap){
            const int dy = tap/3, dx = tap%3;
            int ab[4], asw[4];
            #pragma unroll
            for (int mt=0; mt<4; ++mt){
                int ax = ((mt&1)<<4) + l15 + dx; if (ax > 31) ax = 31;
                int ar = (mt>>1) + dy;
                ab[mt]  = (((ar<<5)+ax)<<8) + (l16<<4);
                asw[mt] = (ax&7)<<4;
            }
            auto step = [&](half8 (&cur)[4], int cib){
                half8 a[4];
                #pragma unroll
                for (int mt=0; mt<4; ++mt)
                    a[mt] = *(const half8*)(const void*)((const char*)Alds + ((ab[mt] + (cib<<6)) ^ asw[mt]));
                #pragma unroll
                for (int mt=0; mt<4; ++mt)
                    #pragma unroll
                    for (int q=0; q<4; ++q)
                        acc[mt][q] = __builtin_amdgcn_mfma_f32_16x16x32_f16(a[mt], cur[q], acc[mt][q], 0, 0, 0);
                if (sl + 2 < 36) gloadq(cur, sl + 2);
                ++sl;
            };
            step(bA, 0); step(bB, 1); step(bA, 2); step(bB, 3);
        }
    }

    // epilogue: + x-conv (fp32 exact) + bias -> gates -> c,h
    float wx[9][4], bq[4];
    #pragma unroll
    for (int tp=0; tp<9; ++tp)
        #pragma unroll
        for (int q=0; q<4; ++q) wx[tp][q] = Wx1[tp*G1 + q*F1 + c];
    #pragma unroll
    for (int q=0; q<4; ++q) bq[q] = b1[q*F1 + c];
    const float* xt = x + ((size_t)(b*NT + t))*E*E;
    #pragma unroll
    for (int mt=0; mt<4; ++mt){
        int py = mt>>1;
        int pxb = ((mt&1)<<4) + (l16<<2);
        int yo = y0 + py;
        #pragma unroll
        for (int r=0; r<4; ++r){
            int px = pxb + r;
            if (px < 30){
                float z0 = acc[mt][0][r] + bq[0];
                float z1 = acc[mt][1][r] + bq[1];
                float z2 = acc[mt][2][r] + bq[2];
                float z3 = acc[mt][3][r] + bq[3];
                #pragma unroll
                for (int dy=0; dy<3; ++dy)
                    #pragma unroll
                    for (int dx=0; dx<3; ++dx){
                        float xv = xt[(yo+dy)*E + px+dx];
                        z0 += xv*wx[dy*3+dx][0]; z1 += xv*wx[dy*3+dx][1];
                        z2 += xv*wx[dy*3+dx][2]; z3 += xv*wx[dy*3+dx][3];
                    }
                float iv = sigf(z0), fv = sigf(z1), gv = tanhf(z2), ov = sigf(z3);
                int idx = ((b*30 + yo)*30 + px)*F1 + c;
                float cn = fv*c_st[idx] + iv*gv;
                c_st[idx] = cn;
                h_out[idx] = (_Float16)(ov*tanhf(cn));
            }
        }
    }
}

// ================= layer-2 MFMA body (one step) =================
// 448 blocks = 8b * 28 rows * 2 ch-halves; 256 thr (4 waves)
__device__ __forceinline__
void l2_body(char* smem, int bid, int tid,
             const _Float16* __restrict__ h1, const _Float16* __restrict__ Wx2t,
             const _Float16* __restrict__ Wh2t, const float* __restrict__ b2,
             const _Float16* __restrict__ h2prev, _Float16* __restrict__ h2out,
             float* __restrict__ c_st, int first)
{
    _Float16* Alds = (_Float16*)smem;     // 3*32*128 fp16 = 24 KB used

    const int nh  = bid & 1;
    const int tmp = bid >> 1;
    const int y0  = tmp % 28;
    const int b   = tmp / 28;

    const int w    = tid >> 6;
    const int lane = tid & 63;
    const int l15  = lane & 15;
    const int l16  = lane >> 4;
    const int c    = nh*64 + w*16 + l15;          // output channel 0..127

    f32x4 acc[2][4];
    #pragma unroll
    for (int mt=0; mt<2; ++mt)
        #pragma unroll
        for (int q=0; q<4; ++q) acc[mt][q] = (f32x4){0.f,0.f,0.f,0.f};

    int grow[4];
    #pragma unroll
    for (int q=0; q<4; ++q) grow[q] = q*128 + nh*64 + w*16 + l15;

    // ---- phase 1: input conv (VALID) over h1 ----
    for (int cih=0; cih<2; ++cih){
        __syncthreads();
        #pragma unroll
        for (int it=0; it<6; ++it){
            int e = tid + (it<<8);
            int ci8 = e & 15, xx = (e>>4)&31, r = e>>9;
            int gy = y0 + r, gx = xx;
            uint4 v = {0u,0u,0u,0u};
            if (gx < 30)
                v = *(const uint4*)(const void*)(h1 + ((((b*30+gy)*30+gx))<<8) + (cih<<7) + (ci8<<3));
            *(uint4*)(void*)((char*)Alds + ((((((r<<5)+xx))<<8) + (ci8<<4)) ^ ((xx&7)<<4))) = v;
        }
        __syncthreads();

        const _Float16* Bc = Wx2t + (cih<<7);
        auto gloadq = [&](half8 (&dst)[4], int nsl){
            const _Float16* src = Bc + (((size_t)(nsl>>2))<<17) + ((nsl&3)<<5);
            #pragma unroll
            for (int q=0; q<4; ++q)
                dst[q] = *(const half8*)(const void*)(src + (grow[q]<<8) + (l16<<3));
        };

        half8 bA[4], bB[4];
        gloadq(bA, 0);
        gloadq(bB, 1);
        int sl = 0;
        for (int tap=0; tap<9; ++tap){
            const int dy = tap/3, dx = tap%3;
            int ab[2], asw[2];
            #pragma unroll
            for (int mt=0; mt<2; ++mt){
                int ax = (mt<<4) + l15 + dx; if (ax > 31) ax = 31;
                ab[mt]  = (((dy<<5)+ax)<<8) + (l16<<4);
                asw[mt] = (ax&7)<<4;
            }
            auto step = [&](half8 (&cur)[4], int cib){
                half8 a[2];
                #pragma unroll
                for (int mt=0; mt<2; ++mt)
                    a[mt] = *(const half8*)(const void*)((const char*)Alds + ((ab[mt] + (cib<<6)) ^ asw[mt]));
                #pragma unroll
                for (int mt=0; mt<2; ++mt)
                    #pragma unroll
                    for (int q=0; q<4; ++q)
                        acc[mt][q] = __builtin_amdgcn_mfma_f32_16x16x32_f16(a[mt], cur[q], acc[mt][q], 0, 0, 0);
                if (sl + 2 < 36) gloadq(cur, sl + 2);
                ++sl;
            };
            step(bA, 0); step(bB, 1); step(bA, 2); step(bB, 3);
        }
    }

    // ---- phase 2: recurrent conv (SAME) over h2prev ----
    if (!first){
        __syncthreads();
        #pragma unroll
        for (int it=0; it<6; ++it){
            int e = tid + (it<<8);
            int ci8 = e & 15, xx = (e>>4)&31, r = e>>9;
            int gy = y0 - 1 + r, gx = xx - 1;
            uint4 v = {0u,0u,0u,0u};
            if (gy >= 0 && gy < 28 && gx >= 0 && gx < 28)
                v = *(const uint4*)(const void*)(h2prev + ((((b*28+gy)*28+gx))<<7) + (ci8<<3));
            *(uint4*)(void*)((char*)Alds + ((((((r<<5)+xx))<<8) + (ci8<<4)) ^ ((xx&7)<<4))) = v;
        }
        __syncthreads();

        auto gloadq = [&](half8 (&dst)[4], int nsl){
            const _Float16* src = Wh2t + (((size_t)(nsl>>2))<<16) + ((nsl&3)<<5);
            #pragma unroll
            for (int q=0; q<4; ++q)
                dst[q] = *(const half8*)(const void*)(src + (grow[q]<<7) + (l16<<3));
        };

        half8 bA[4], bB[4];
        gloadq(bA, 0);
        gloadq(bB, 1);
        int sl = 0;
        for (int tap=0; tap<9; ++tap){
            const int dy = tap/3, dx = tap%3;
            int ab[2], asw[2];
            #pragma unroll
            for (int mt=0; mt<2; ++mt){
                int ax = (mt<<4) + l15 + dx; if (ax > 31) ax = 31;
                ab[mt]  = (((dy<<5)+ax)<<8) + (l16<<4);
                asw[mt] = (ax&7)<<4;
            }
            auto step = [&](half8 (&cur)[4], int cib){
                half8 a[2];
                #pragma unroll
                for (int mt=0; mt<2; ++mt)
                    a[mt] = *(const half8*)(const void*)((const char*)Alds + ((ab[mt] + (cib<<6)) ^ asw[mt]));
                #pragma unroll
                for (int mt=0; mt<2; ++mt)
                    #pragma unroll
                    for (int q=0; q<4; ++q)
                        acc[mt][q] = __builtin_amdgcn_mfma_f32_16x16x32_f16(a[mt], cur[q], acc[mt][q], 0, 0, 0);
                if (sl + 2 < 36) gloadq(cur, sl + 2);
                ++sl;
            };
            step(bA, 0); step(bB, 1); step(bA, 2); step(bB, 3);
        }
    }

    // epilogue
    float bq[4];
    #pragma unroll
    for (int q=0; q<4; ++q) bq[q] = b2[q*F2 + c];
    #pragma unroll
    for (int mt=0; mt<2; ++mt){
        #pragma unroll
        for (int r=0; r<4; ++r){
            int px = (mt<<4) + (l16<<2) + r;
            if (px < 28){
                float z0 = acc[mt][0][r] + bq[0];
                float z1 = acc[mt][1][r] + bq[1];
                float z2 = acc[mt][2][r] + bq[2];
                float z3 = acc[mt][3][r] + bq[3];
                float iv = sigf(z0), fv = sigf(z1), gv = tanhf(z2), ov = sigf(z3);
                int idx = ((b*28 + y0)*28 + px)*F2 + c;
                float cold = first ? 0.0f : c_st[idx];
                float cn = fv*cold + iv*gv;
                c_st[idx] = cn;
                h2out[idx] = (_Float16)(ov*tanhf(cn));
            }
        }
    }
}

// ================= fused: l2(t) [blocks 0..447] + l1(t+1) [448..927] =================
__global__ __launch_bounds__(256, 3)
void fused_step(const float* __restrict__ x, const _Float16* __restrict__ Wh1t,
                const float* __restrict__ Wx1, const float* __restrict__ b1,
                const _Float16* __restrict__ h1_cur, _Float16* __restrict__ h1_nxt,
                float* __restrict__ c1,
                const _Float16* __restrict__ Wx2t, const _Float16* __restrict__ Wh2t,
                const float* __restrict__ b2,
                const _Float16* __restrict__ h2_prev, _Float16* __restrict__ h2_out,
                float* __restrict__ c2, int t, int first)
{
    __shared__ char smem[32768];
    const int bid = blockIdx.x;
    if (bid < 448)
        l2_body(smem, bid, threadIdx.x, h1_cur, Wx2t, Wh2t, b2, h2_prev, h2_out, c2, first);
    else
        l1_body(smem, bid - 448, threadIdx.x, x, Wh1t, Wx1, b1, h1_cur, h1_nxt, c1, t + 1);
}

// standalone l2 for the final step (t=9)
__global__ __launch_bounds__(256, 3)
void l2_mfma(const _Float16* __restrict__ h1, const _Float16* __restrict__ Wx2t,
             const _Float16* __restrict__ Wh2t, const float* __restrict__ b2,
             const _Float16* __restrict__ h2prev, _Float16* __restrict__ h2out,
             float* __restrict__ c_st, int first)
{
    __shared__ char smem[24576];
    l2_body(smem, blockIdx.x, threadIdx.x, h1, Wx2t, Wh2t, b2, h2prev, h2out, c_st, first);
}

// ================= fused: weight transpose + layer-1 t=0 =================
__global__ __launch_bounds__(256)
void prep_t0(const float* __restrict__ Wh1, const float* __restrict__ Wx2,
             const float* __restrict__ Wh2, _Float16* __restrict__ Wh1t,
             _Float16* __restrict__ Wx2t, _Float16* __restrict__ Wh2t,
             const float* __restrict__ x, const float* __restrict__ Wx1,
             const float* __restrict__ b1, _Float16* __restrict__ h_out,
             float* __restrict__ c_st)
{
    if (blockIdx.x < 16128){
        int i = blockIdx.x*256 + threadIdx.x;
        if (i < 2359296){                      // Wh1t: (tap*1024+g)*256+ci
            int ci = i & 255, g = (i>>8) & 1023, tap = i>>18;
            Wh1t[i] = (_Float16)Wh1[(tap*256 + ci)*1024 + g];
        } else if (i < 2359296 + 1179648){     // Wx2t
            int j = i - 2359296;
            int ci = j & 255, g = (j>>8) & 511, tap = j>>17;
            Wx2t[j] = (_Float16)Wx2[(tap*256 + ci)*512 + g];
        } else if (i < 2359296 + 1179648 + 589824){  // Wh2t
            int j = i - (2359296 + 1179648);
            int ci = j & 127, g = (j>>7) & 511, tap = j>>16;
            Wh2t[j] = (_Float16)Wh2[(tap*128 + ci)*512 + g];
        }
        return;
    }
    const int bid = blockIdx.x - 16128;  // 240 = 8*30
    const int y = bid % 30, b = bid / 30;
    const int c = threadIdx.x;
    float wx[9][4], bq[4];
    #pragma unroll
    for (int tp=0; tp<9; ++tp)
        #pragma unroll
        for (int q=0; q<4; ++q) wx[tp][q] = Wx1[tp*G1 + q*F1 + c];
    #pragma unroll
    for (int q=0; q<4; ++q) bq[q] = b1[q*F1 + c];
    const float* xt = x + ((size_t)b*NT)*E*E;   // t=0
    for (int px=0; px<30; ++px){
        float z0=bq[0], z1=bq[1], z2=bq[2], z3=bq[3];
        #pragma unroll
        for (int dy=0; dy<3; ++dy)
            #pragma unroll
            for (int dx=0; dx<3; ++dx){
                float xv = xt[(y+dy)*E + px+dx];
                z0 += xv*wx[dy*3+dx][0]; z1 += xv*wx[dy*3+dx][1];
                z2 += xv*wx[dy*3+dx][2]; z3 += xv*wx[dy*3+dx][3];
            }
        float iv = sigf(z0), gv = tanhf(z2), ov = sigf(z3);
        int idx = ((b*30 + y)*30 + px)*F1 + c;
        float cn = iv*gv;
        c_st[idx] = cn;
        h_out[idx] = (_Float16)(ov*tanhf(cn));
    }
}

// ---------------- dense head / fcs ----------------
__global__ __launch_bounds__(256)
void dense1_k(const _Float16* __restrict__ h2, const float* __restrict__ W,
              const float* __restrict__ bv, float* __restrict__ out)
{
    __shared__ float row[F2];
    int r = blockIdx.x;
    int j = threadIdx.x;
    if (j < F2) row[j] = (float)h2[(size_t)r*F2 + j];
    __syncthreads();
    float s = bv[j];
    #pragma unroll 8
    for (int k=0; k<F2; ++k) s += row[k]*W[(size_t)k*256 + j];
    out[(size_t)r*256 + j] = s > 0.f ? s : 0.f;
}

__global__ __launch_bounds__(256)
void dense2_k(const float* __restrict__ in, const float* __restrict__ W,
              const float* __restrict__ bv, float* __restrict__ cat)
{
    int tid = threadIdx.x;
    int j  = tid & 63;
    int rl = tid >> 6;
    int r = blockIdx.x*4 + rl;
    const float* irow = in + (size_t)r*256;
    float s = bv[j];
    #pragma unroll 8
    for (int k=0; k<256; ++k) s += irow[k]*W[(size_t)k*64 + j];
    int b   = r / (H2*W2);
    int rem = r % (H2*W2);
    int yy  = rem / W2;
    int xx  = rem % W2;
    float v = s > 0.f ? s : 0.f;
    cat[(((size_t)b*30 + yy)*W2 + xx)*64 + j] = v;
}

__global__ void copy_tl_k(const float* __restrict__ tin, const float* __restrict__ lin,
                          float* __restrict__ cat)
{
    int i = blockIdx.x*blockDim.x + threadIdx.x;
    const int n = NB*W2*64;
    if (i < 2*n){
        const float* src = (i < n) ? tin : lin;
        int ii   = (i < n) ? i : i - n;
        int yrow = (i < n) ? 28 : 29;
        int b    = ii / (W2*64);
        int rem  = ii % (W2*64);
        cat[(((size_t)b*30 + yrow)*W2)*64 + rem] = src[ii];
    }
}

__global__ __launch_bounds__(256)
void fc1_k(const float* __restrict__ in, const float* __restrict__ W,
           const float* __restrict__ bv, float* __restrict__ out)
{
    int tid = threadIdx.x;
    int j  = tid & 63;
    int rl = tid >> 6;
    int r = blockIdx.x*4 + rl;
    const float* irow = in + (size_t)r*64;
    float s = bv[j];
    #pragma unroll 8
    for (int k=0; k<64; ++k) s += irow[k]*W[(size_t)k*64 + j];
    out[(size_t)r*64 + j] = s > 0.f ? s : 0.f;
}

__global__ __launch_bounds__(256)
void fc2_k(const float* __restrict__ in, const float* __restrict__ W,
           const float* __restrict__ bv, float* __restrict__ out)
{
    int tid  = threadIdx.x;
    int lane = tid & 63;
    int r = blockIdx.x*4 + (tid >> 6);
    float v = in[(size_t)r*64 + lane] * W[lane];
    #pragma unroll
    for (int s=32; s>0; s>>=1) v += __shfl_down(v, s, 64);
    if (lane == 0) out[r] = v + bv[0];
}

extern "C" void kernel_launch(void* const* d_in, const int* in_sizes, int n_in,
                              void* d_out, int out_size, void* d_ws, size_t ws_size,
                              hipStream_t stream)
{
    (void)in_sizes; (void)n_in; (void)out_size; (void)ws_size;
    const float* x   = (const float*)d_in[0];
    const float* tin = (const float*)d_in[1];
    const float* lin = (const float*)d_in[2];
    const float* Wx1 = (const float*)d_in[3];
    const float* Wh1 = (const float*)d_in[4];
    const float* b1  = (const float*)d_in[5];
    const float* Wx2 = (const float*)d_in[6];
    const float* Wh2 = (const float*)d_in[7];
    const float* b2  = (const float*)d_in[8];
    const float* Wd1 = (const float*)d_in[9];
    const float* bd1 = (const float*)d_in[10];
    const float* Wd2 = (const float*)d_in[11];
    const float* bd2 = (const float*)d_in[12];
    const float* Wf1 = (const float*)d_in[13];
    const float* bf1 = (const float*)d_in[14];
    const float* Wf2 = (const float*)d_in[15];
    const float* bf2 = (const float*)d_in[16];
    float* out = (float*)d_out;

    // workspace layout (bytes), total 29,425,664 B
    char* p = (char*)d_ws;
    _Float16* h1a  = (_Float16*)p; p += 3686400;
    _Float16* h1b  = (_Float16*)p; p += 3686400;
    float*    c1   = (float*)p;    p += 7372800;
    _Float16* h2a  = (_Float16*)p; p += 1605632;
    _Float16* h2b  = (_Float16*)p; p += 1605632;
    float*    c2   = (float*)p;    p += 3211264;
    _Float16* Wh1t = (_Float16*)p; p += 4718592;
    _Float16* Wx2t = (_Float16*)p; p += 2359296;
    _Float16* Wh2t = (_Float16*)p; p += 1179648;
    // head buffers alias dead LSTM state
    float* d1o = c1;            // 6272*256 fp32 = 6.42 MB <= 7.37 MB
    float* cat = (float*)h1a;   // 430080 fp32 = 1.72 MB <= 3.69 MB
    float* f1o = (float*)h1b;   // 1.72 MB <= 3.69 MB

    _Float16* h1w[2] = {h1a, h1b};
    _Float16* h2w[2] = {h2a, h2b};

    // prep_w + l1(t=0) fused (independent)
    prep_t0<<<16368, 256, 0, stream>>>(Wh1, Wx2, Wh2, Wh1t, Wx2t, Wh2t,
                                       x, Wx1, b1, h1w[0], c1);
    // F(t) = l2(t) + l1(t+1), t = 0..8   (both depend only on h1(t))
    for (int t=0; t<9; ++t){
        fused_step<<<928, 256, 0, stream>>>(
            x, Wh1t, Wx1, b1,
            h1w[t&1], h1w[(t+1)&1], c1,
            Wx2t, Wh2t, b2,
            h2w[(t+1)&1], h2w[t&1], c2,
            t, t==0);
    }
    // final l2(9): reads h1(9)=h1w[1], h2(8)=h2w[0] -> writes h2w[1]
    l2_mfma<<<448, 256, 0, stream>>>(h1w[1], Wx2t, Wh2t, b2, h2w[0], h2w[1], c2, 0);

    dense1_k<<<6272, 256, 0, stream>>>(h2w[1], Wd1, bd1, d1o);
    dense2_k<<<1568, 256, 0, stream>>>(d1o, Wd2, bd2, cat);
    copy_tl_k<<<(2*NB*W2*64 + 255)/256, 256, 0, stream>>>(tin, lin, cat);
    fc1_k<<<1680, 256, 0, stream>>>(cat, Wf1, bf1, f1o);
    fc2_k<<<1680, 256, 0, stream>>>(f1o, Wf2, bf2, out);
}

// Round 9
// 2127.562 us; speedup vs baseline: 1.1704x; 1.1704x over previous
//
#include <hip/hip_runtime.h>
#include <math.h>

static constexpr int NB = 8, NT = 10, E = 32;
static constexpr int H1 = 30, W1 = 30, F1 = 256, G1 = 1024;
static constexpr int H2 = 28, W2 = 28, F2 = 128, G2 = 512;

typedef _Float16 half8 __attribute__((ext_vector_type(8)));
typedef float f32x4 __attribute__((ext_vector_type(4)));

__device__ __forceinline__ float sigf(float v){ return 1.0f/(1.0f + __expf(-v)); }

// ---------- layer-1 MFMA step (t>=1) ----------
// grid 480; XCD-swizzled decomposition: quadrant nq from bid&7 so all blocks
// sharing a B panel land on 2 XCDs (panel 1.18 MB < 4 MB L2).
// 4-deep global->reg B pipeline; A staged in LDS.
__global__ __launch_bounds__(256, 3)
void l1_mfma(const float* __restrict__ x, const _Float16* __restrict__ Wh1t,
             const float* __restrict__ Wx1, const float* __restrict__ b1,
             const _Float16* __restrict__ h_prev, _Float16* __restrict__ h_out,
             float* __restrict__ c_st, int t)
{
    __shared__ _Float16 Alds[4*32*128];   // 32 KB

    const int bid = blockIdx.x;
    const int nq  = (bid & 7) >> 1;                  // quadrant -> XCD pair
    const int sub = (bid & 1) + ((bid >> 3) << 1);   // 0..119
    const int rp  = sub % 15;
    const int b   = sub / 15;
    const int y0  = rp*2;

    const int tid  = threadIdx.x;
    const int w    = tid >> 6;
    const int lane = tid & 63;
    const int l15  = lane & 15;
    const int l16  = lane >> 4;
    const int c    = nq*64 + w*16 + l15;          // output channel 0..255

    f32x4 acc[4][4];
    #pragma unroll
    for (int mt=0; mt<4; ++mt)
        #pragma unroll
        for (int q=0; q<4; ++q) acc[mt][q] = (f32x4){0.f,0.f,0.f,0.f};

    int goff[4];
    #pragma unroll
    for (int q=0; q<4; ++q) goff[q] = ((q*256 + nq*64 + w*16 + l15)<<8) + (l16<<3);

    for (int cih=0; cih<2; ++cih){
        __syncthreads();
        #pragma unroll
        for (int it=0; it<8; ++it){
            int e = tid + (it<<8);
            int ci8 = e & 15, xx = (e>>4)&31, r = e>>9;
            int gy = y0 - 1 + r, gx = xx - 1;
            uint4 v = {0u,0u,0u,0u};
            if (gy >= 0 && gy < 30 && gx >= 0 && gx < 30)
                v = *(const uint4*)(const void*)(h_prev + ((((b*30+gy)*30+gx))<<8) + (cih<<7) + (ci8<<3));
            *(uint4*)(void*)((char*)Alds + ((((((r<<5)+xx))<<8) + (ci8<<4)) ^ ((xx&7)<<4))) = v;
        }
        __syncthreads();

        const _Float16* Bc = Wh1t + (cih<<7);
        auto gloadq = [&](half8 (&dst)[4], int nsl){
            const _Float16* src = Bc + (((size_t)(nsl>>2))<<18) + ((nsl&3)<<5);
            #pragma unroll
            for (int q=0; q<4; ++q)
                dst[q] = *(const half8*)(const void*)(src + goff[q]);
        };

        half8 p0[4], p1[4], p2[4], p3[4];
        gloadq(p0, 0); gloadq(p1, 1); gloadq(p2, 2); gloadq(p3, 3);
        int sl = 0;
        for (int tap=0; tap<9; ++tap){
            const int dy = tap/3, dx = tap%3;
            int ab[4], asw[4];
            #pragma unroll
            for (int mt=0; mt<4; ++mt){
                int ax = ((mt&1)<<4) + l15 + dx; if (ax > 31) ax = 31;
                int ar = (mt>>1) + dy;
                ab[mt]  = (((ar<<5)+ax)<<8) + (l16<<4);
                asw[mt] = (ax&7)<<4;
            }
            auto step = [&](half8 (&cur)[4], int cib){
                half8 a[4];
                #pragma unroll
                for (int mt=0; mt<4; ++mt)
                    a[mt] = *(const half8*)(const void*)((const char*)Alds + ((ab[mt] + (cib<<6)) ^ asw[mt]));
                #pragma unroll
                for (int mt=0; mt<4; ++mt)
                    #pragma unroll
                    for (int q=0; q<4; ++q)
                        acc[mt][q] = __builtin_amdgcn_mfma_f32_16x16x32_f16(a[mt], cur[q], acc[mt][q], 0, 0, 0);
                if (sl + 4 < 36) gloadq(cur, sl + 4);   // 4-deep: refill after use
                ++sl;
            };
            step(p0, 0); step(p1, 1); step(p2, 2); step(p3, 3);
        }
    }

    // epilogue: + x-conv (fp32 exact) + bias -> gates -> c,h
    float wx[9][4], bq[4];
    #pragma unroll
    for (int tp=0; tp<9; ++tp)
        #pragma unroll
        for (int q=0; q<4; ++q) wx[tp][q] = Wx1[tp*G1 + q*F1 + c];
    #pragma unroll
    for (int q=0; q<4; ++q) bq[q] = b1[q*F1 + c];
    const float* xt = x + ((size_t)(b*NT + t))*E*E;
    #pragma unroll
    for (int mt=0; mt<4; ++mt){
        int py = mt>>1;
        int pxb = ((mt&1)<<4) + (l16<<2);
        int yo = y0 + py;
        #pragma unroll
        for (int r=0; r<4; ++r){
            int px = pxb + r;
            if (px < 30){
                float z0 = acc[mt][0][r] + bq[0];
                float z1 = acc[mt][1][r] + bq[1];
                float z2 = acc[mt][2][r] + bq[2];
                float z3 = acc[mt][3][r] + bq[3];
                #pragma unroll
                for (int dy=0; dy<3; ++dy)
                    #pragma unroll
                    for (int dx=0; dx<3; ++dx){
                        float xv = xt[(yo+dy)*E + px+dx];
                        z0 += xv*wx[dy*3+dx][0]; z1 += xv*wx[dy*3+dx][1];
                        z2 += xv*wx[dy*3+dx][2]; z3 += xv*wx[dy*3+dx][3];
                    }
                float iv = sigf(z0), fv = sigf(z1), gv = tanhf(z2), ov = sigf(z3);
                int idx = ((b*30 + yo)*30 + px)*F1 + c;
                float cn = fv*c_st[idx] + iv*gv;
                c_st[idx] = cn;
                h_out[idx] = (_Float16)(ov*tanhf(cn));
            }
        }
    }
}

// ---------- layer-2 MFMA step ----------
// grid 448; XCD-swizzled: ch-half nh from bid&7 (panel 1.77 MB per 4 XCDs).
__global__ __launch_bounds__(256, 3)
void l2_mfma(const _Float16* __restrict__ h1, const _Float16* __restrict__ Wx2t,
             const _Float16* __restrict__ Wh2t, const float* __restrict__ b2,
             const _Float16* __restrict__ h2prev, _Float16* __restrict__ h2out,
             float* __restrict__ c_st, int first)
{
    __shared__ _Float16 Alds[3*32*128];   // 24 KB

    const int bid = blockIdx.x;
    const int nh  = (bid & 7) >> 2;                  // ch-half -> XCD quad
    const int sub = (bid & 3) + ((bid >> 3) << 2);   // 0..223
    const int y0  = sub % 28;
    const int b   = sub / 28;

    const int tid  = threadIdx.x;
    const int w    = tid >> 6;
    const int lane = tid & 63;
    const int l15  = lane & 15;
    const int l16  = lane >> 4;
    const int c    = nh*64 + w*16 + l15;          // output channel 0..127

    f32x4 acc[2][4];
    #pragma unroll
    for (int mt=0; mt<2; ++mt)
        #pragma unroll
        for (int q=0; q<4; ++q) acc[mt][q] = (f32x4){0.f,0.f,0.f,0.f};

    int grow[4];
    #pragma unroll
    for (int q=0; q<4; ++q) grow[q] = q*128 + nh*64 + w*16 + l15;

    // ---- phase 1: input conv (VALID) over h1 ----
    for (int cih=0; cih<2; ++cih){
        __syncthreads();
        #pragma unroll
        for (int it=0; it<6; ++it){
            int e = tid + (it<<8);
            int ci8 = e & 15, xx = (e>>4)&31, r = e>>9;
            int gy = y0 + r, gx = xx;
            uint4 v = {0u,0u,0u,0u};
            if (gx < 30)
                v = *(const uint4*)(const void*)(h1 + ((((b*30+gy)*30+gx))<<8) + (cih<<7) + (ci8<<3));
            *(uint4*)(void*)((char*)Alds + ((((((r<<5)+xx))<<8) + (ci8<<4)) ^ ((xx&7)<<4))) = v;
        }
        __syncthreads();

        const _Float16* Bc = Wx2t + (cih<<7);
        auto gloadq = [&](half8 (&dst)[4], int nsl){
            const _Float16* src = Bc + (((size_t)(nsl>>2))<<17) + ((nsl&3)<<5);
            #pragma unroll
            for (int q=0; q<4; ++q)
                dst[q] = *(const half8*)(const void*)(src + (grow[q]<<8) + (l16<<3));
        };

        half8 p0[4], p1[4], p2[4], p3[4];
        gloadq(p0, 0); gloadq(p1, 1); gloadq(p2, 2); gloadq(p3, 3);
        int sl = 0;
        for (int tap=0; tap<9; ++tap){
            const int dy = tap/3, dx = tap%3;
            int ab[2], asw[2];
            #pragma unroll
            for (int mt=0; mt<2; ++mt){
                int ax = (mt<<4) + l15 + dx; if (ax > 31) ax = 31;
                ab[mt]  = (((dy<<5)+ax)<<8) + (l16<<4);
                asw[mt] = (ax&7)<<4;
            }
            auto step = [&](half8 (&cur)[4], int cib){
                half8 a[2];
                #pragma unroll
                for (int mt=0; mt<2; ++mt)
                    a[mt] = *(const half8*)(const void*)((const char*)Alds + ((ab[mt] + (cib<<6)) ^ asw[mt]));
                #pragma unroll
                for (int mt=0; mt<2; ++mt)
                    #pragma unroll
                    for (int q=0; q<4; ++q)
                        acc[mt][q] = __builtin_amdgcn_mfma_f32_16x16x32_f16(a[mt], cur[q], acc[mt][q], 0, 0, 0);
                if (sl + 4 < 36) gloadq(cur, sl + 4);
                ++sl;
            };
            step(p0, 0); step(p1, 1); step(p2, 2); step(p3, 3);
        }
    }

    // ---- phase 2: recurrent conv (SAME) over h2prev ----
    if (!first){
        __syncthreads();
        #pragma unroll
        for (int it=0; it<6; ++it){
            int e = tid + (it<<8);
            int ci8 = e & 15, xx = (e>>4)&31, r = e>>9;
            int gy = y0 - 1 + r, gx = xx - 1;
            uint4 v = {0u,0u,0u,0u};
            if (gy >= 0 && gy < 28 && gx >= 0 && gx < 28)
                v = *(const uint4*)(const void*)(h2prev + ((((b*28+gy)*28+gx))<<7) + (ci8<<3));
            *(uint4*)(void*)((char*)Alds + ((((((r<<5)+xx))<<8) + (ci8<<4)) ^ ((xx&7)<<4))) = v;
        }
        __syncthreads();

        auto gloadq = [&](half8 (&dst)[4], int nsl){
            const _Float16* src = Wh2t + (((size_t)(nsl>>2))<<16) + ((nsl&3)<<5);
            #pragma unroll
            for (int q=0; q<4; ++q)
                dst[q] = *(const half8*)(const void*)(src + (grow[q]<<7) + (l16<<3));
        };

        half8 p0[4], p1[4], p2[4], p3[4];
        gloadq(p0, 0); gloadq(p1, 1); gloadq(p2, 2); gloadq(p3, 3);
        int sl = 0;
        for (int tap=0; tap<9; ++tap){
            const int dy = tap/3, dx = tap%3;
            int ab[2], asw[2];
            #pragma unroll
            for (int mt=0; mt<2; ++mt){
                int ax = (mt<<4) + l15 + dx; if (ax > 31) ax = 31;
                ab[mt]  = (((dy<<5)+ax)<<8) + (l16<<4);
                asw[mt] = (ax&7)<<4;
            }
            auto step = [&](half8 (&cur)[4], int cib){
                half8 a[2];
                #pragma unroll
                for (int mt=0; mt<2; ++mt)
                    a[mt] = *(const half8*)(const void*)((const char*)Alds + ((ab[mt] + (cib<<6)) ^ asw[mt]));
                #pragma unroll
                for (int mt=0; mt<2; ++mt)
                    #pragma unroll
                    for (int q=0; q<4; ++q)
                        acc[mt][q] = __builtin_amdgcn_mfma_f32_16x16x32_f16(a[mt], cur[q], acc[mt][q], 0, 0, 0);
                if (sl + 4 < 36) gloadq(cur, sl + 4);
                ++sl;
            };
            step(p0, 0); step(p1, 1); step(p2, 2); step(p3, 3);
        }
    }

    // epilogue
    float bq[4];
    #pragma unroll
    for (int q=0; q<4; ++q) bq[q] = b2[q*F2 + c];
    #pragma unroll
    for (int mt=0; mt<2; ++mt){
        #pragma unroll
        for (int r=0; r<4; ++r){
            int px = (mt<<4) + (l16<<2) + r;
            if (px < 28){
                float z0 = acc[mt][0][r] + bq[0];
                float z1 = acc[mt][1][r] + bq[1];
                float z2 = acc[mt][2][r] + bq[2];
                float z3 = acc[mt][3][r] + bq[3];
                float iv = sigf(z0), fv = sigf(z1), gv = tanhf(z2), ov = sigf(z3);
                int idx = ((b*28 + y0)*28 + px)*F2 + c;
                float cold = first ? 0.0f : c_st[idx];
                float cn = fv*cold + iv*gv;
                c_st[idx] = cn;
                h2out[idx] = (_Float16)(ov*tanhf(cn));
            }
        }
    }
}

// ================= fused: weight transpose + layer-1 t=0 =================
__global__ __launch_bounds__(256)
void prep_t0(const float* __restrict__ Wh1, const float* __restrict__ Wx2,
             const float* __restrict__ Wh2, _Float16* __restrict__ Wh1t,
             _Float16* __restrict__ Wx2t, _Float16* __restrict__ Wh2t,
             const float* __restrict__ x, const float* __restrict__ Wx1,
             const float* __restrict__ b1, _Float16* __restrict__ h_out,
             float* __restrict__ c_st)
{
    if (blockIdx.x < 16128){
        int i = blockIdx.x*256 + threadIdx.x;
        if (i < 2359296){                      // Wh1t: (tap*1024+g)*256+ci
            int ci = i & 255, g = (i>>8) & 1023, tap = i>>18;
            Wh1t[i] = (_Float16)Wh1[(tap*256 + ci)*1024 + g];
        } else if (i < 2359296 + 1179648){     // Wx2t
            int j = i - 2359296;
            int ci = j & 255, g = (j>>8) & 511, tap = j>>17;
            Wx2t[j] = (_Float16)Wx2[(tap*256 + ci)*512 + g];
        } else if (i < 2359296 + 1179648 + 589824){  // Wh2t
            int j = i - (2359296 + 1179648);
            int ci = j & 127, g = (j>>7) & 511, tap = j>>16;
            Wh2t[j] = (_Float16)Wh2[(tap*128 + ci)*512 + g];
        }
        return;
    }
    const int bid = blockIdx.x - 16128;  // 240 = 8*30
    const int y = bid % 30, b = bid / 30;
    const int c = threadIdx.x;
    float wx[9][4], bq[4];
    #pragma unroll
    for (int tp=0; tp<9; ++tp)
        #pragma unroll
        for (int q=0; q<4; ++q) wx[tp][q] = Wx1[tp*G1 + q*F1 + c];
    #pragma unroll
    for (int q=0; q<4; ++q) bq[q] = b1[q*F1 + c];
    const float* xt = x + ((size_t)b*NT)*E*E;   // t=0
    for (int px=0; px<30; ++px){
        float z0=bq[0], z1=bq[1], z2=bq[2], z3=bq[3];
        #pragma unroll
        for (int dy=0; dy<3; ++dy)
            #pragma unroll
            for (int dx=0; dx<3; ++dx){
                float xv = xt[(y+dy)*E + px+dx];
                z0 += xv*wx[dy*3+dx][0]; z1 += xv*wx[dy*3+dx][1];
                z2 += xv*wx[dy*3+dx][2]; z3 += xv*wx[dy*3+dx][3];
            }
        float iv = sigf(z0), gv = tanhf(z2), ov = sigf(z3);
        int idx = ((b*30 + y)*30 + px)*F1 + c;
        float cn = iv*gv;
        c_st[idx] = cn;
        h_out[idx] = (_Float16)(ov*tanhf(cn));
    }
}

// ---------------- dense head / fcs ----------------
__global__ __launch_bounds__(256)
void dense1_k(const _Float16* __restrict__ h2, const float* __restrict__ W,
              const float* __restrict__ bv, float* __restrict__ out)
{
    __shared__ float row[F2];
    int r = blockIdx.x;
    int j = threadIdx.x;
    if (j < F2) row[j] = (float)h2[(size_t)r*F2 + j];
    __syncthreads();
    float s = bv[j];
    #pragma unroll 8
    for (int k=0; k<F2; ++k) s += row[k]*W[(size_t)k*256 + j];
    out[(size_t)r*256 + j] = s > 0.f ? s : 0.f;
}

__global__ __launch_bounds__(256)
void dense2_k(const float* __restrict__ in, const float* __restrict__ W,
              const float* __restrict__ bv, float* __restrict__ cat)
{
    int tid = threadIdx.x;
    int j  = tid & 63;
    int rl = tid >> 6;
    int r = blockIdx.x*4 + rl;
    const float* irow = in + (size_t)r*256;
    float s = bv[j];
    #pragma unroll 8
    for (int k=0; k<256; ++k) s += irow[k]*W[(size_t)k*64 + j];
    int b   = r / (H2*W2);
    int rem = r % (H2*W2);
    int yy  = rem / W2;
    int xx  = rem % W2;
    float v = s > 0.f ? s : 0.f;
    cat[(((size_t)b*30 + yy)*W2 + xx)*64 + j] = v;
}

__global__ void copy_tl_k(const float* __restrict__ tin, const float* __restrict__ lin,
                          float* __restrict__ cat)
{
    int i = blockIdx.x*blockDim.x + threadIdx.x;
    const int n = NB*W2*64;
    if (i < 2*n){
        const float* src = (i < n) ? tin : lin;
        int ii   = (i < n) ? i : i - n;
        int yrow = (i < n) ? 28 : 29;
        int b    = ii / (W2*64);
        int rem  = ii % (W2*64);
        cat[(((size_t)b*30 + yrow)*W2)*64 + rem] = src[ii];
    }
}

__global__ __launch_bounds__(256)
void fc1_k(const float* __restrict__ in, const float* __restrict__ W,
           const float* __restrict__ bv, float* __restrict__ out)
{
    int tid = threadIdx.x;
    int j  = tid & 63;
    int rl = tid >> 6;
    int r = blockIdx.x*4 + rl;
    const float* irow = in + (size_t)r*64;
    float s = bv[j];
    #pragma unroll 8
    for (int k=0; k<64; ++k) s += irow[k]*W[(size_t)k*64 + j];
    out[(size_t)r*64 + j] = s > 0.f ? s : 0.f;
}

__global__ __launch_bounds__(256)
void fc2_k(const float* __restrict__ in, const float* __restrict__ W,
           const float* __restrict__ bv, float* __restrict__ out)
{
    int tid  = threadIdx.x;
    int lane = tid & 63;
    int r = blockIdx.x*4 + (tid >> 6);
    float v = in[(size_t)r*64 + lane] * W[lane];
    #pragma unroll
    for (int s=32; s>0; s>>=1) v += __shfl_down(v, s, 64);
    if (lane == 0) out[r] = v + bv[0];
}

extern "C" void kernel_launch(void* const* d_in, const int* in_sizes, int n_in,
                              void* d_out, int out_size, void* d_ws, size_t ws_size,
                              hipStream_t stream)
{
    (void)in_sizes; (void)n_in; (void)out_size; (void)ws_size;
    const float* x   = (const float*)d_in[0];
    const float* tin = (const float*)d_in[1];
    const float* lin = (const float*)d_in[2];
    const float* Wx1 = (const float*)d_in[3];
    const float* Wh1 = (const float*)d_in[4];
    const float* b1  = (const float*)d_in[5];
    const float* Wx2 = (const float*)d_in[6];
    const float* Wh2 = (const float*)d_in[7];
    const float* b2  = (const float*)d_in[8];
    const float* Wd1 = (const float*)d_in[9];
    const float* bd1 = (const float*)d_in[10];
    const float* Wd2 = (const float*)d_in[11];
    const float* bd2 = (const float*)d_in[12];
    const float* Wf1 = (const float*)d_in[13];
    const float* bf1 = (const float*)d_in[14];
    const float* Wf2 = (const float*)d_in[15];
    const float* bf2 = (const float*)d_in[16];
    float* out = (float*)d_out;

    // workspace layout (bytes), total 29,425,664 B
    char* p = (char*)d_ws;
    _Float16* h1a  = (_Float16*)p; p += 3686400;
    _Float16* h1b  = (_Float16*)p; p += 3686400;
    float*    c1   = (float*)p;    p += 7372800;
    _Float16* h2a  = (_Float16*)p; p += 1605632;
    _Float16* h2b  = (_Float16*)p; p += 1605632;
    float*    c2   = (float*)p;    p += 3211264;
    _Float16* Wh1t = (_Float16*)p; p += 4718592;
    _Float16* Wx2t = (_Float16*)p; p += 2359296;
    _Float16* Wh2t = (_Float16*)p; p += 1179648;
    // head buffers alias dead LSTM state
    float* d1o = c1;            // 6272*256 fp32 = 6.42 MB <= 7.37 MB
    float* cat = (float*)h1a;   // 430080 fp32 = 1.72 MB <= 3.69 MB
    float* f1o = (float*)h1b;   // 1.72 MB <= 3.69 MB

    _Float16* h1w[2] = {h1a, h1b};
    _Float16* h2w[2] = {h2a, h2b};

    prep_t0<<<16368, 256, 0, stream>>>(Wh1, Wx2, Wh2, Wh1t, Wx2t, Wh2t,
                                       x, Wx1, b1, h1w[0], c1);
    l2_mfma<<<448, 256, 0, stream>>>(h1w[0], Wx2t, Wh2t, b2, h2w[0], h2w[0], c2, 1);
    for (int t=1; t<NT; ++t){
        l1_mfma<<<480, 256, 0, stream>>>(x, Wh1t, Wx1, b1, h1w[(t-1)&1], h1w[t&1], c1, t);
        l2_mfma<<<448, 256, 0, stream>>>(h1w[t&1], Wx2t, Wh2t, b2, h2w[(t-1)&1], h2w[t&1], c2, 0);
    }
    // t=9 wrote h2w[1]
    dense1_k<<<6272, 256, 0, stream>>>(h2w[1], Wd1, bd1, d1o);
    dense2_k<<<1568, 256, 0, stream>>>(d1o, Wd2, bd2, cat);
    copy_tl_k<<<(2*NB*W2*64 + 255)/256, 256, 0, stream>>>(tin, lin, cat);
    fc1_k<<<1680, 256, 0, stream>>>(cat, Wf1, bf1, f1o);
    fc2_k<<<1680, 256, 0, stream>>>(f1o, Wf2, bf2, out);
}

// Round 10
// 1309.981 us; speedup vs baseline: 1.9009x; 1.6241x over previous
//
#include <hip/hip_runtime.h>
#include <math.h>

static constexpr int NB = 8, NT = 10, E = 32;
static constexpr int H1 = 30, W1 = 30, F1 = 256, G1 = 1024;
static constexpr int H2 = 28, W2 = 28, F2 = 128, G2 = 512;

typedef _Float16 half8 __attribute__((ext_vector_type(8)));
typedef float f32x4 __attribute__((ext_vector_type(4)));

__device__ __forceinline__ float sigf(float v){ return 1.0f/(1.0f + __expf(-v)); }

// ---------- layer-1 MFMA step (t>=1) ----------
// grid 256 = 8b * 8 row-quads * 4 ch-quadrants; 512 thr (8 waves = 2 row-pairs x 4 ch-groups)
// Block tile: M=128 (4 rows x 32 px), N=256 (64 ch x 4 gates). B staged once per
// block into LDS (double-buffered 32-k slices) -> B L2-demand 566->302 MB/step.
__global__ __launch_bounds__(512)
void l1_mfma(const float* __restrict__ x, const _Float16* __restrict__ Wh1t,
             const float* __restrict__ Wx1, const float* __restrict__ b1,
             const _Float16* __restrict__ h_prev, _Float16* __restrict__ h_out,
             float* __restrict__ c_st, int t)
{
    __shared__ _Float16 Alds[6*32*64];      // 24 KB: rows y0-1..y0+4, 64-ci group
    __shared__ _Float16 Blds[2][256*32];    // 2 x 16 KB: 256 gate-rows x 32 k

    const int bid = blockIdx.x;
    const int nq  = bid & 3;
    const int rq  = (bid >> 2) & 7;
    const int b   = bid >> 5;
    const int y0  = rq*4;

    const int tid  = threadIdx.x;
    const int w    = tid >> 6;
    const int wm   = w >> 2;        // 0..1: row pair within the 4-row tile
    const int wn   = w & 3;         // 0..3: 16-ch group within quadrant
    const int lane = tid & 63;
    const int l15  = lane & 15;
    const int l16  = lane >> 4;
    const int c    = nq*64 + wn*16 + l15;     // output channel 0..255

    f32x4 acc[4][4];
    #pragma unroll
    for (int mt=0; mt<4; ++mt)
        #pragma unroll
        for (int q=0; q<4; ++q) acc[mt][q] = (f32x4){0.f,0.f,0.f,0.f};

    int boff[4];
    #pragma unroll
    for (int q=0; q<4; ++q){
        int gl = q*64 + wn*16 + l15;
        boff[q] = ((gl<<6) + (l16<<4)) ^ ((gl&7)<<4);
    }

    // B staging constants: thread covers row rB, 32B half hB of a 256x64B slice
    const int rB  = tid >> 1, hB = tid & 1;
    const int gB  = (rB>>6)*256 + nq*64 + (rB&63);   // global gate row
    const int dB0 = ((rB<<6) + (hB<<5)) ^ ((rB&7)<<4);
    const int dB1 = ((rB<<6) + (hB<<5) + 16) ^ ((rB&7)<<4);
    uint4 pv0, pv1;

    for (int cih=0; cih<4; ++cih){            // 64-ci groups
        // ---- A stage (prev readers done at loop-end barrier) ----
        #pragma unroll
        for (int it=0; it<3; ++it){
            int e = tid + (it<<9);
            int ci8 = e & 7, xx = (e>>3)&31, r = e>>8;
            int gy = y0 - 1 + r, gx = xx - 1;
            uint4 v = {0u,0u,0u,0u};
            if (gy >= 0 && gy < 30 && gx >= 0 && gx < 30)
                v = *(const uint4*)(const void*)(h_prev + ((size_t)((b*30+gy)*30+gx)<<8) + (cih<<6) + (ci8<<3));
            *(uint4*)(void*)((char*)Alds + (((((r<<5)+xx)<<7) + (ci8<<4)) ^ ((xx&7)<<4))) = v;
        }
        // ---- B prologue: slice 0 ----
        {
            const _Float16* src = Wh1t + ((size_t)gB<<8) + (cih<<6) + (hB<<4);
            pv0 = *(const uint4*)(const void*)src;
            pv1 = *(const uint4*)(const void*)(src + 8);
        }
        __syncthreads();
        {
            char* dst = (char*)Blds;
            *(uint4*)(void*)(dst + dB0) = pv0;
            *(uint4*)(void*)(dst + dB1) = pv1;
        }
        __syncthreads();
        int cur = 0;
        for (int nsl=0; nsl<18; ++nsl){       // 9 taps x 2 cib
            const int nx = nsl + 1;
            if (nx < 18){
                int tap = nx>>1, cib = nx&1;
                const _Float16* src = Wh1t + ((size_t)(tap*1024 + gB)<<8) + (cih<<6) + (cib<<5) + (hB<<4);
                pv0 = *(const uint4*)(const void*)src;
                pv1 = *(const uint4*)(const void*)(src + 8);
            }
            {
                const int tap = nsl>>1, cib = nsl&1;
                const int dy = tap/3, dx = tap%3;
                half8 a[4], bb[4];
                #pragma unroll
                for (int mt=0; mt<4; ++mt){
                    int ax = ((mt&1)<<4) + l15 + dx; if (ax > 31) ax = 31;
                    int ar = 2*wm + (mt>>1) + dy;
                    a[mt] = *(const half8*)(const void*)((const char*)Alds +
                            (((((ar<<5)+ax)<<7) + (cib<<6) + (l16<<4)) ^ ((ax&7)<<4)));
                }
                const char* bp = (const char*)Blds + (cur<<14);
                #pragma unroll
                for (int q=0; q<4; ++q)
                    bb[q] = *(const half8*)(const void*)(bp + boff[q]);
                #pragma unroll
                for (int mt=0; mt<4; ++mt)
                    #pragma unroll
                    for (int q=0; q<4; ++q)
                        acc[mt][q] = __builtin_amdgcn_mfma_f32_16x16x32_f16(a[mt], bb[q], acc[mt][q], 0, 0, 0);
            }
            if (nx < 18){
                char* dst = (char*)Blds + ((cur^1)<<14);
                *(uint4*)(void*)(dst + dB0) = pv0;
                *(uint4*)(void*)(dst + dB1) = pv1;
            }
            __syncthreads();
            cur ^= 1;
        }
    }

    // epilogue: + x-conv (fp32 exact) + bias -> gates -> c,h
    float wx[9][4], bq[4];
    #pragma unroll
    for (int tp=0; tp<9; ++tp)
        #pragma unroll
        for (int q=0; q<4; ++q) wx[tp][q] = Wx1[tp*G1 + q*F1 + c];
    #pragma unroll
    for (int q=0; q<4; ++q) bq[q] = b1[q*F1 + c];
    const float* xt = x + ((size_t)(b*NT + t))*E*E;
    #pragma unroll
    for (int mt=0; mt<4; ++mt){
        int py  = mt>>1;
        int pxb = ((mt&1)<<4) + (l16<<2);
        int yo  = y0 + 2*wm + py;
        #pragma unroll
        for (int r=0; r<4; ++r){
            int px = pxb + r;
            if (px < 30 && yo < 30){
                float z0 = acc[mt][0][r] + bq[0];
                float z1 = acc[mt][1][r] + bq[1];
                float z2 = acc[mt][2][r] + bq[2];
                float z3 = acc[mt][3][r] + bq[3];
                #pragma unroll
                for (int dy=0; dy<3; ++dy)
                    #pragma unroll
                    for (int dx=0; dx<3; ++dx){
                        float xv = xt[(yo+dy)*E + px+dx];
                        z0 += xv*wx[dy*3+dx][0]; z1 += xv*wx[dy*3+dx][1];
                        z2 += xv*wx[dy*3+dx][2]; z3 += xv*wx[dy*3+dx][3];
                    }
                float iv = sigf(z0), fv = sigf(z1), gv = tanhf(z2), ov = sigf(z3);
                int idx = ((b*30 + yo)*30 + px)*F1 + c;
                float cn = fv*c_st[idx] + iv*gv;
                c_st[idx] = cn;
                h_out[idx] = (_Float16)(ov*tanhf(cn));
            }
        }
    }
}

// ---------- layer-2 MFMA step ----------
// grid 224 = 8b * 7 row-quads * 4 ch-quarters; 512 thr (8 waves = 4 rows x 2 ch-groups)
// Block tile: M=128 (4 rows x 32 px), N=128 (32 ch x 4 gates). B demand 762->194 MB.
__global__ __launch_bounds__(512)
void l2_mfma(const _Float16* __restrict__ h1, const _Float16* __restrict__ Wx2t,
             const _Float16* __restrict__ Wh2t, const float* __restrict__ b2,
             const _Float16* __restrict__ h2prev, _Float16* __restrict__ h2out,
             float* __restrict__ c_st, int first)
{
    __shared__ _Float16 Alds[6*32*64];      // 24 KB
    __shared__ _Float16 Blds[2][128*32];    // 2 x 8 KB

    const int bid = blockIdx.x;
    const int qc  = bid & 3;                // 32-ch quarter
    const int t2  = bid >> 2;
    const int rq  = t2 % 7;
    const int b   = t2 / 7;
    const int y0  = rq*4;

    const int tid  = threadIdx.x;
    const int w    = tid >> 6;
    const int wm   = w >> 1;       // 0..3: row within 4-row tile
    const int wn   = w & 1;        // 0..1: 16-ch group within quarter
    const int lane = tid & 63;
    const int l15  = lane & 15;
    const int l16  = lane >> 4;
    const int c    = qc*32 + wn*16 + l15;    // output channel 0..127

    f32x4 acc[2][4];
    #pragma unroll
    for (int mt=0; mt<2; ++mt)
        #pragma unroll
        for (int q=0; q<4; ++q) acc[mt][q] = (f32x4){0.f,0.f,0.f,0.f};

    int boff[4];
    #pragma unroll
    for (int q=0; q<4; ++q){
        int gl = q*32 + wn*16 + l15;
        boff[q] = ((gl<<6) + (l16<<4)) ^ ((gl&7)<<4);
    }

    // B staging: thread covers row rB (0..127), 16B quarter qB of a 128x64B slice
    const int rB = tid >> 2, qB = tid & 3;
    const int gB = (rB>>5)*128 + qc*32 + (rB&31);
    const int dB = ((rB<<6) + (qB<<4)) ^ ((rB&7)<<4);
    uint4 pv;

    // ---- phase 1: input conv (VALID) over h1, ci 256 in 4 groups ----
    for (int cih=0; cih<4; ++cih){
        #pragma unroll
        for (int it=0; it<3; ++it){
            int e = tid + (it<<9);
            int ci8 = e & 7, xx = (e>>3)&31, r = e>>8;
            int gy = y0 + r, gx = xx;
            uint4 v = {0u,0u,0u,0u};
            if (gy < 30 && gx < 30)
                v = *(const uint4*)(const void*)(h1 + ((size_t)((b*30+gy)*30+gx)<<8) + (cih<<6) + (ci8<<3));
            *(uint4*)(void*)((char*)Alds + (((((r<<5)+xx)<<7) + (ci8<<4)) ^ ((xx&7)<<4))) = v;
        }
        {
            const _Float16* src = Wx2t + ((size_t)gB<<8) + (cih<<6) + (qB<<3);
            pv = *(const uint4*)(const void*)src;
        }
        __syncthreads();
        *(uint4*)(void*)((char*)Blds + dB) = pv;
        __syncthreads();
        int cur = 0;
        for (int nsl=0; nsl<18; ++nsl){
            const int nx = nsl + 1;
            if (nx < 18){
                int tap = nx>>1, cib = nx&1;
                const _Float16* src = Wx2t + ((size_t)(tap*512 + gB)<<8) + (cih<<6) + (cib<<5) + (qB<<3);
                pv = *(const uint4*)(const void*)src;
            }
            {
                const int tap = nsl>>1, cib = nsl&1;
                const int dy = tap/3, dx = tap%3;
                half8 a[2], bb[4];
                #pragma unroll
                for (int mt=0; mt<2; ++mt){
                    int ax = (mt<<4) + l15 + dx; if (ax > 31) ax = 31;
                    int ar = wm + dy;
                    a[mt] = *(const half8*)(const void*)((const char*)Alds +
                            (((((ar<<5)+ax)<<7) + (cib<<6) + (l16<<4)) ^ ((ax&7)<<4)));
                }
                const char* bp = (const char*)Blds + (cur<<13);
                #pragma unroll
                for (int q=0; q<4; ++q)
                    bb[q] = *(const half8*)(const void*)(bp + boff[q]);
                #pragma unroll
                for (int mt=0; mt<2; ++mt)
                    #pragma unroll
                    for (int q=0; q<4; ++q)
                        acc[mt][q] = __builtin_amdgcn_mfma_f32_16x16x32_f16(a[mt], bb[q], acc[mt][q], 0, 0, 0);
            }
            if (nx < 18)
                *(uint4*)(void*)((char*)Blds + ((cur^1)<<13) + dB) = pv;
            __syncthreads();
            cur ^= 1;
        }
    }

    // ---- phase 2: recurrent conv (SAME) over h2prev, ci 128 in 2 groups ----
    if (!first){
        for (int cih=0; cih<2; ++cih){
            #pragma unroll
            for (int it=0; it<3; ++it){
                int e = tid + (it<<9);
                int ci8 = e & 7, xx = (e>>3)&31, r = e>>8;
                int gy = y0 - 1 + r, gx = xx - 1;
                uint4 v = {0u,0u,0u,0u};
                if (gy >= 0 && gy < 28 && gx >= 0 && gx < 28)
                    v = *(const uint4*)(const void*)(h2prev + ((size_t)((b*28+gy)*28+gx)<<7) + (cih<<6) + (ci8<<3));
                *(uint4*)(void*)((char*)Alds + (((((r<<5)+xx)<<7) + (ci8<<4)) ^ ((xx&7)<<4))) = v;
            }
            {
                const _Float16* src = Wh2t + ((size_t)gB<<7) + (cih<<6) + (qB<<3);
                pv = *(const uint4*)(const void*)src;
            }
            __syncthreads();
            *(uint4*)(void*)((char*)Blds + dB) = pv;
            __syncthreads();
            int cur = 0;
            for (int nsl=0; nsl<18; ++nsl){
                const int nx = nsl + 1;
                if (nx < 18){
                    int tap = nx>>1, cib = nx&1;
                    const _Float16* src = Wh2t + ((size_t)(tap*512 + gB)<<7) + (cih<<6) + (cib<<5) + (qB<<3);
                    pv = *(const uint4*)(const void*)src;
                }
                {
                    const int tap = nsl>>1, cib = nsl&1;
                    const int dy = tap/3, dx = tap%3;
                    half8 a[2], bb[4];
                    #pragma unroll
                    for (int mt=0; mt<2; ++mt){
                        int ax = (mt<<4) + l15 + dx; if (ax > 31) ax = 31;
                        int ar = wm + dy;
                        a[mt] = *(const half8*)(const void*)((const char*)Alds +
                                (((((ar<<5)+ax)<<7) + (cib<<6) + (l16<<4)) ^ ((ax&7)<<4)));
                    }
                    const char* bp = (const char*)Blds + (cur<<13);
                    #pragma unroll
                    for (int q=0; q<4; ++q)
                        bb[q] = *(const half8*)(const void*)(bp + boff[q]);
                    #pragma unroll
                    for (int mt=0; mt<2; ++mt)
                        #pragma unroll
                        for (int q=0; q<4; ++q)
                            acc[mt][q] = __builtin_amdgcn_mfma_f32_16x16x32_f16(a[mt], bb[q], acc[mt][q], 0, 0, 0);
                }
                if (nx < 18)
                    *(uint4*)(void*)((char*)Blds + ((cur^1)<<13) + dB) = pv;
                __syncthreads();
                cur ^= 1;
            }
        }
    }

    // epilogue
    float bq[4];
    #pragma unroll
    for (int q=0; q<4; ++q) bq[q] = b2[q*F2 + c];
    const int yo = y0 + wm;
    #pragma unroll
    for (int mt=0; mt<2; ++mt){
        #pragma unroll
        for (int r=0; r<4; ++r){
            int px = (mt<<4) + (l16<<2) + r;
            if (px < 28){
                float z0 = acc[mt][0][r] + bq[0];
                float z1 = acc[mt][1][r] + bq[1];
                float z2 = acc[mt][2][r] + bq[2];
                float z3 = acc[mt][3][r] + bq[3];
                float iv = sigf(z0), fv = sigf(z1), gv = tanhf(z2), ov = sigf(z3);
                int idx = ((b*28 + yo)*28 + px)*F2 + c;
                float cold = first ? 0.0f : c_st[idx];
                float cn = fv*cold + iv*gv;
                c_st[idx] = cn;
                h2out[idx] = (_Float16)(ov*tanhf(cn));
            }
        }
    }
}

// ================= fused: weight transpose + layer-1 t=0 =================
__global__ __launch_bounds__(256)
void prep_t0(const float* __restrict__ Wh1, const float* __restrict__ Wx2,
             const float* __restrict__ Wh2, _Float16* __restrict__ Wh1t,
             _Float16* __restrict__ Wx2t, _Float16* __restrict__ Wh2t,
             const float* __restrict__ x, const float* __restrict__ Wx1,
             const float* __restrict__ b1, _Float16* __restrict__ h_out,
             float* __restrict__ c_st)
{
    if (blockIdx.x < 16128){
        int i = blockIdx.x*256 + threadIdx.x;
        if (i < 2359296){                      // Wh1t: (tap*1024+g)*256+ci
            int ci = i & 255, g = (i>>8) & 1023, tap = i>>18;
            Wh1t[i] = (_Float16)Wh1[(tap*256 + ci)*1024 + g];
        } else if (i < 2359296 + 1179648){     // Wx2t
            int j = i - 2359296;
            int ci = j & 255, g = (j>>8) & 511, tap = j>>17;
            Wx2t[j] = (_Float16)Wx2[(tap*256 + ci)*512 + g];
        } else if (i < 2359296 + 1179648 + 589824){  // Wh2t
            int j = i - (2359296 + 1179648);
            int ci = j & 127, g = (j>>7) & 511, tap = j>>16;
            Wh2t[j] = (_Float16)Wh2[(tap*128 + ci)*512 + g];
        }
        return;
    }
    const int bid = blockIdx.x - 16128;  // 240 = 8*30
    const int y = bid % 30, b = bid / 30;
    const int c = threadIdx.x;
    float wx[9][4], bq[4];
    #pragma unroll
    for (int tp=0; tp<9; ++tp)
        #pragma unroll
        for (int q=0; q<4; ++q) wx[tp][q] = Wx1[tp*G1 + q*F1 + c];
    #pragma unroll
    for (int q=0; q<4; ++q) bq[q] = b1[q*F1 + c];
    const float* xt = x + ((size_t)b*NT)*E*E;   // t=0
    for (int px=0; px<30; ++px){
        float z0=bq[0], z1=bq[1], z2=bq[2], z3=bq[3];
        #pragma unroll
        for (int dy=0; dy<3; ++dy)
            #pragma unroll
            for (int dx=0; dx<3; ++dx){
                float xv = xt[(y+dy)*E + px+dx];
                z0 += xv*wx[dy*3+dx][0]; z1 += xv*wx[dy*3+dx][1];
                z2 += xv*wx[dy*3+dx][2]; z3 += xv*wx[dy*3+dx][3];
            }
        float iv = sigf(z0), gv = tanhf(z2), ov = sigf(z3);
        int idx = ((b*30 + y)*30 + px)*F1 + c;
        float cn = iv*gv;
        c_st[idx] = cn;
        h_out[idx] = (_Float16)(ov*tanhf(cn));
    }
}

// ---------------- dense head / fcs ----------------
__global__ __launch_bounds__(256)
void dense1_k(const _Float16* __restrict__ h2, const float* __restrict__ W,
              const float* __restrict__ bv, float* __restrict__ out)
{
    __shared__ float row[F2];
    int r = blockIdx.x;
    int j = threadIdx.x;
    if (j < F2) row[j] = (float)h2[(size_t)r*F2 + j];
    __syncthreads();
    float s = bv[j];
    #pragma unroll 8
    for (int k=0; k<F2; ++k) s += row[k]*W[(size_t)k*256 + j];
    out[(size_t)r*256 + j] = s > 0.f ? s : 0.f;
}

__global__ __launch_bounds__(256)
void dense2_k(const float* __restrict__ in, const float* __restrict__ W,
              const float* __restrict__ bv, float* __restrict__ cat)
{
    int tid = threadIdx.x;
    int j  = tid & 63;
    int rl = tid >> 6;
    int r = blockIdx.x*4 + rl;
    const float* irow = in + (size_t)r*256;
    float s = bv[j];
    #pragma unroll 8
    for (int k=0; k<256; ++k) s += irow[k]*W[(size_t)k*64 + j];
    int b   = r / (H2*W2);
    int rem = r % (H2*W2);
    int yy  = rem / W2;
    int xx  = rem % W2;
    float v = s > 0.f ? s : 0.f;
    cat[(((size_t)b*30 + yy)*W2 + xx)*64 + j] = v;
}

__global__ void copy_tl_k(const float* __restrict__ tin, const float* __restrict__ lin,
                          float* __restrict__ cat)
{
    int i = blockIdx.x*blockDim.x + threadIdx.x;
    const int n = NB*W2*64;
    if (i < 2*n){
        const float* src = (i < n) ? tin : lin;
        int ii   = (i < n) ? i : i - n;
        int yrow = (i < n) ? 28 : 29;
        int b    = ii / (W2*64);
        int rem  = ii % (W2*64);
        cat[(((size_t)b*30 + yrow)*W2)*64 + rem] = src[ii];
    }
}

__global__ __launch_bounds__(256)
void fc1_k(const float* __restrict__ in, const float* __restrict__ W,
           const float* __restrict__ bv, float* __restrict__ out)
{
    int tid = threadIdx.x;
    int j  = tid & 63;
    int rl = tid >> 6;
    int r = blockIdx.x*4 + rl;
    const float* irow = in + (size_t)r*64;
    float s = bv[j];
    #pragma unroll 8
    for (int k=0; k<64; ++k) s += irow[k]*W[(size_t)k*64 + j];
    out[(size_t)r*64 + j] = s > 0.f ? s : 0.f;
}

__global__ __launch_bounds__(256)
void fc2_k(const float* __restrict__ in, const float* __restrict__ W,
           const float* __restrict__ bv, float* __restrict__ out)
{
    int tid  = threadIdx.x;
    int lane = tid & 63;
    int r = blockIdx.x*4 + (tid >> 6);
    float v = in[(size_t)r*64 + lane] * W[lane];
    #pragma unroll
    for (int s=32; s>0; s>>=1) v += __shfl_down(v, s, 64);
    if (lane == 0) out[r] = v + bv[0];
}

extern "C" void kernel_launch(void* const* d_in, const int* in_sizes, int n_in,
                              void* d_out, int out_size, void* d_ws, size_t ws_size,
                              hipStream_t stream)
{
    (void)in_sizes; (void)n_in; (void)out_size; (void)ws_size;
    const float* x   = (const float*)d_in[0];
    const float* tin = (const float*)d_in[1];
    const float* lin = (const float*)d_in[2];
    const float* Wx1 = (const float*)d_in[3];
    const float* Wh1 = (const float*)d_in[4];
    const float* b1  = (const float*)d_in[5];
    const float* Wx2 = (const float*)d_in[6];
    const float* Wh2 = (const float*)d_in[7];
    const float* b2  = (const float*)d_in[8];
    const float* Wd1 = (const float*)d_in[9];
    const float* bd1 = (const float*)d_in[10];
    const float* Wd2 = (const float*)d_in[11];
    const float* bd2 = (const float*)d_in[12];
    const float* Wf1 = (const float*)d_in[13];
    const float* bf1 = (const float*)d_in[14];
    const float* Wf2 = (const float*)d_in[15];
    const float* bf2 = (const float*)d_in[16];
    float* out = (float*)d_out;

    // workspace layout (bytes), total 29,425,664 B
    char* p = (char*)d_ws;
    _Float16* h1a  = (_Float16*)p; p += 3686400;
    _Float16* h1b  = (_Float16*)p; p += 3686400;
    float*    c1   = (float*)p;    p += 7372800;
    _Float16* h2a  = (_Float16*)p; p += 1605632;
    _Float16* h2b  = (_Float16*)p; p += 1605632;
    float*    c2   = (float*)p;    p += 3211264;
    _Float16* Wh1t = (_Float16*)p; p += 4718592;
    _Float16* Wx2t = (_Float16*)p; p += 2359296;
    _Float16* Wh2t = (_Float16*)p; p += 1179648;
    // head buffers alias dead LSTM state
    float* d1o = c1;            // 6272*256 fp32 = 6.42 MB <= 7.37 MB
    float* cat = (float*)h1a;   // 430080 fp32 = 1.72 MB <= 3.69 MB
    float* f1o = (float*)h1b;   // 1.72 MB <= 3.69 MB

    _Float16* h1w[2] = {h1a, h1b};
    _Float16* h2w[2] = {h2a, h2b};

    prep_t0<<<16368, 256, 0, stream>>>(Wh1, Wx2, Wh2, Wh1t, Wx2t, Wh2t,
                                       x, Wx1, b1, h1w[0], c1);
    l2_mfma<<<224, 512, 0, stream>>>(h1w[0], Wx2t, Wh2t, b2, h2w[0], h2w[0], c2, 1);
    for (int t=1; t<NT; ++t){
        l1_mfma<<<256, 512, 0, stream>>>(x, Wh1t, Wx1, b1, h1w[(t-1)&1], h1w[t&1], c1, t);
        l2_mfma<<<224, 512, 0, stream>>>(h1w[t&1], Wx2t, Wh2t, b2, h2w[(t-1)&1], h2w[t&1], c2, 0);
    }
    // t=9 wrote h2w[1]
    dense1_k<<<6272, 256, 0, stream>>>(h2w[1], Wd1, bd1, d1o);
    dense2_k<<<1568, 256, 0, stream>>>(d1o, Wd2, bd2, cat);
    copy_tl_k<<<(2*NB*W2*64 + 255)/256, 256, 0, stream>>>(tin, lin, cat);
    fc1_k<<<1680, 256, 0, stream>>>(cat, Wf1, bf1, f1o);
    fc2_k<<<1680, 256, 0, stream>>>(f1o, Wf2, bf2, out);
}